// Round 12
// baseline (216.349 us; speedup 1.0000x reference)
//
#include <hip/hip_runtime.h>
#include <hip/hip_bf16.h>

#define NH 16
#define NKV 4
#define HD 128
// ATT_SCALE * log2(e): Q pre-scaled so P = exp2(S_mfma)
#define QSCALE 0.1275174272f

using bf16x8 = __attribute__((ext_vector_type(8))) __bf16;
using f32x4  = __attribute__((ext_vector_type(4))) float;
using u16x8  = __attribute__((ext_vector_type(8))) unsigned short;
using u16x2  = __attribute__((ext_vector_type(2))) unsigned short;

__device__ __forceinline__ unsigned short f2b(float f) {
  __hip_bfloat16 h = __float2bfloat16(f);
  return __builtin_bit_cast(unsigned short, h);
}
__device__ __forceinline__ float b2f(unsigned short u) {
  unsigned int v = ((unsigned int)u) << 16;
  return __builtin_bit_cast(float, v);
}

__device__ __forceinline__ void glds16(const unsigned short* g, unsigned short* l) {
  __builtin_amdgcn_global_load_lds(
      (const __attribute__((address_space(1))) unsigned int*)(const void*)g,
      (__attribute__((address_space(3))) unsigned int*)(void*)l, 16, 0, 0);
}

// ---------------- fused fp32 -> bf16 conversion (8 elems/thread) ----------
__global__ __launch_bounds__(256) void cvt_fused(const float* __restrict__ x,
                                                 const float* __restrict__ wq,
                                                 const float* __restrict__ wk,
                                                 const float* __restrict__ wv,
                                                 const float* __restrict__ wo,
                                                 unsigned short* __restrict__ xb,
                                                 unsigned short* __restrict__ wqkvb,
                                                 unsigned short* __restrict__ wob) {
  int i = blockIdx.x * 256 + threadIdx.x;
  const float* src;
  unsigned short* dst;
  int off;
  if (i < 1048576)      { src = x;  dst = xb;              off = i; }
  else if (i < 1572864) { src = wq; dst = wqkvb;           off = i - 1048576; }
  else if (i < 1703936) { src = wk; dst = wqkvb + 4194304; off = i - 1572864; }
  else if (i < 1835008) { src = wv; dst = wqkvb + 5242880; off = i - 1703936; }
  else                  { src = wo; dst = wob;             off = i - 1835008; }
  const float4* s4 = reinterpret_cast<const float4*>(src) + (size_t)off * 2;
  float4 v0 = s4[0], v1 = s4[1];
  u16x8 o;
  o[0] = f2b(v0.x); o[1] = f2b(v0.y); o[2] = f2b(v0.z); o[3] = f2b(v0.w);
  o[4] = f2b(v1.x); o[5] = f2b(v1.y); o[6] = f2b(v1.z); o[7] = f2b(v1.w);
  reinterpret_cast<u16x8*>(dst)[off] = o;
}

// ---------------- GEMM 256x256, m201 quadrant schedule --------------------
// C[M,N] = A[M,K]*B[N,K]^T. BM=BN=256, BK=64. 512 thr = 8 waves (2M x 4N),
// wave out = 128x64 (acc[8][4]). Per K-tile: 4 phases, phase q =
// {ds_read A-quadrant (4 b128) [+ all B (8) at q0] | stage 1 half-tile
// (2 glds) | barrier | lgkmcnt(0) | setprio | 16 MFMA | setprio | barrier}.
// Stage stream per tile t: q0:Ah0(t+1) q1:Ah1(t+1) q2:Bh0(t+2) q3:Bh1(t+2);
// boundary vmcnt(4) leaves exactly B(t+2)'s 4 loads in flight (T4).
// Hazards: WAR - overwritten regions' ds_reads completed (lgkm0) >=2
// barriers earlier; RAW - boundary wait drains A(t+1),B(t+1). LDS 128 KB
// (2 buf x [256][64] x 2 operands). Swizzle: phys chunk = c ^ (row&7),
// inverse on glds source (T2, 0 conflicts measured R6-R11).
template<int CF32>
__global__ __launch_bounds__(512, 1) void gemm_q(const unsigned short* __restrict__ A,
                                                 const unsigned short* __restrict__ B,
                                                 void* __restrict__ C,
                                                 int N, int K, int nbx) {
  __shared__ unsigned short As[2][256 * 64];
  __shared__ unsigned short Bs[2][256 * 64];
  const int tid = threadIdx.x, lane = tid & 63;
  const int wid = tid >> 6, wm = wid >> 2, wn = wid & 3;
  const int cpx = gridDim.x >> 3;       // bijective XCD swizzle (grid%8==0)
  const int wgid = (blockIdx.x & 7) * cpx + (blockIdx.x >> 3);
  const int bx = wgid % nbx, by = wgid / nbx;
  const int row0 = by * 256, col0 = bx * 256;
  const int fr = lane & 15, g = lane >> 4;
  const int NT = K >> 6;

  // stage source offsets (inverse-swizzled). chunk cid = h*1024 + l*512 + tid:
  // row = cid>>3, phys = cid&7, logical k-chunk cl = phys ^ (row&7).
  size_t offA[2][2], offB[2][2];
#pragma unroll
  for (int h = 0; h < 2; h++)
#pragma unroll
    for (int l = 0; l < 2; l++) {
      int cid = h * 1024 + l * 512 + tid;
      int row = cid >> 3, phys = cid & 7, cl = phys ^ (row & 7);
      offA[h][l] = (size_t)(row0 + row) * K + cl * 8;
      offB[h][l] = (size_t)(col0 + row) * K + cl * 8;
    }

  auto stA = [&](int t, int h) {
    int k0 = t * 64, sb = t & 1;
    glds16(A + offA[h][0] + k0, &As[sb][(h * 1024 + tid) * 8]);
    glds16(A + offA[h][1] + k0, &As[sb][(h * 1024 + 512 + tid) * 8]);
  };
  auto stB = [&](int t, int h) {
    int k0 = t * 64, sb = t & 1;
    glds16(B + offB[h][0] + k0, &Bs[sb][(h * 1024 + tid) * 8]);
    glds16(B + offB[h][1] + k0, &Bs[sb][(h * 1024 + 512 + tid) * 8]);
  };

  // fragment read: logical chunk c = ks*4+g at row -> phys = c ^ (row&7)
  auto ldfrag = [&](const unsigned short* buf, int row, int ks) {
    int phys = ((ks << 2) | g) ^ (row & 7);
    return *reinterpret_cast<const bf16x8*>(&buf[row * 64 + phys * 8]);
  };

  f32x4 acc[8][4];
#pragma unroll
  for (int i = 0; i < 8; i++)
#pragma unroll
    for (int j = 0; j < 4; j++) acc[i][j] = f32x4{0.f, 0.f, 0.f, 0.f};

  // prologue: A(0) both halves, B(0) both, B(1) both = 12 loads;
  // vmcnt(4) leaves B(1)'s 4 in flight, drains A(0)+B(0).
  stA(0, 0); stA(0, 1);
  stB(0, 0); stB(0, 1);
  stB(1, 0); stB(1, 1);
  asm volatile("s_waitcnt vmcnt(4)" ::: "memory");
  __builtin_amdgcn_s_barrier();
  __builtin_amdgcn_sched_barrier(0);

#pragma unroll 1
  for (int t = 0; t < NT; ++t) {
    const int rb = t & 1;
    const unsigned short* Ar = &As[rb][0];
    const unsigned short* Br = &Bs[rb][0];
    bf16x8 bfr[4][2];
#pragma unroll
    for (int q = 0; q < 4; ++q) {
      bf16x8 a[2][2];
#pragma unroll
      for (int i = 0; i < 2; ++i) {
        int row = wm * 128 + (2 * q + i) * 16 + fr;
        a[i][0] = ldfrag(Ar, row, 0);
        a[i][1] = ldfrag(Ar, row, 1);
      }
      if (q == 0) {
#pragma unroll
        for (int nf = 0; nf < 4; ++nf) {
          int row = wn * 64 + nf * 16 + fr;
          bfr[nf][0] = ldfrag(Br, row, 0);
          bfr[nf][1] = ldfrag(Br, row, 1);
        }
      }
      // half-tile stage woven into the phase
      if (q < 2)  { if (t + 1 < NT) stA(t + 1, q); }
      else        { if (t + 2 < NT) stB(t + 2, q - 2); }
      __builtin_amdgcn_s_barrier();
      asm volatile("s_waitcnt lgkmcnt(0)" ::: "memory");
      __builtin_amdgcn_sched_barrier(0);
      __builtin_amdgcn_s_setprio(1);
#pragma unroll
      for (int i = 0; i < 2; ++i)
#pragma unroll
        for (int nf = 0; nf < 4; ++nf) {
          acc[2 * q + i][nf] = __builtin_amdgcn_mfma_f32_16x16x32_bf16(a[i][0], bfr[nf][0], acc[2 * q + i][nf], 0, 0, 0);
          acc[2 * q + i][nf] = __builtin_amdgcn_mfma_f32_16x16x32_bf16(a[i][1], bfr[nf][1], acc[2 * q + i][nf], 0, 0, 0);
        }
      __builtin_amdgcn_s_setprio(0);
      __builtin_amdgcn_sched_barrier(0);
      __builtin_amdgcn_s_barrier();
    }
    // K-tile boundary: drain A(t+1)+B(t+1), keep B(t+2) in flight
    if (t + 1 < NT) {
      if (t + 2 < NT) asm volatile("s_waitcnt vmcnt(4)" ::: "memory");
      else            asm volatile("s_waitcnt vmcnt(0)" ::: "memory");
      __builtin_amdgcn_s_barrier();
      __builtin_amdgcn_sched_barrier(0);
    }
  }

  // epilogue
#pragma unroll
  for (int i = 0; i < 8; i++) {
#pragma unroll
    for (int j = 0; j < 4; j++) {
      int rbase = row0 + wm * 128 + i * 16 + g * 4;
      int cb = col0 + wn * 64 + j * 16 + fr;
#pragma unroll
      for (int r = 0; r < 4; r++) {
        if (CF32)
          reinterpret_cast<float*>(C)[(size_t)(rbase + r) * N + cb] = acc[i][j][r];
        else
          reinterpret_cast<unsigned short*>(C)[(size_t)(rbase + r) * N + cb] = f2b(acc[i][j][r]);
      }
    }
  }
}

// ---------------- RoPE (reads fused qkv [4096][3072]) ---------------------
__global__ __launch_bounds__(256) void rope_kernel(const unsigned short* __restrict__ qkv,
                                                   const float* __restrict__ freqs,
                                                   unsigned short* __restrict__ qro,
                                                   unsigned short* __restrict__ kro,
                                                   float* __restrict__ newk) {
  const int NQ = 4096 * 16 * 64;
  const int NK = 4096 * 4 * 64;
  int idx = blockIdx.x * 256 + threadIdx.x;
  if (idx >= NQ + NK) return;
  if (idx < NQ) {
    int i = idx & 63;
    int h = (idx >> 6) & 15;
    int row = idx >> 10;             // b*2048 + s
    int s = row & 2047, b = row >> 11;
    float f = freqs[s * 64 + i];
    float c = cosf(f), sn = sinf(f);
    u16x2 xv = *reinterpret_cast<const u16x2*>(qkv + (size_t)row * 3072 + h * 128 + 2 * i);
    float x1 = b2f(xv.x), x2 = b2f(xv.y);
    float r1 = (x1 * c - x2 * sn) * QSCALE;
    float r2 = (x1 * sn + x2 * c) * QSCALE;
    u16x2 o; o.x = f2b(r1); o.y = f2b(r2);
    *reinterpret_cast<u16x2*>(qro + ((size_t)(b * 16 + h) * 2048 + s) * 128 + 2 * i) = o;
  } else {
    idx -= NQ;
    int i = idx & 63;
    int h = (idx >> 6) & 3;
    int row = idx >> 8;
    int s = row & 2047, b = row >> 11;
    float f = freqs[s * 64 + i];
    float c = cosf(f), sn = sinf(f);
    u16x2 xv = *reinterpret_cast<const u16x2*>(qkv + (size_t)row * 3072 + 2048 + h * 128 + 2 * i);
    float x1 = b2f(xv.x), x2 = b2f(xv.y);
    float r1 = x1 * c - x2 * sn;
    float r2 = x1 * sn + x2 * c;
    u16x2 o; o.x = f2b(r1); o.y = f2b(r2);
    *reinterpret_cast<u16x2*>(kro + ((size_t)(b * 4 + h) * 2048 + s) * 128 + 2 * i) = o;
    float2 of; of.x = r1; of.y = r2;
    *reinterpret_cast<float2*>(newk + (size_t)row * 512 + h * 128 + 2 * i) = of;
  }
}

// ---------------- V: LDS-tiled transpose -> vt[B][KVH][D][S] (slot-permuted)
__global__ __launch_bounds__(256) void vtrans_kernel(const unsigned short* __restrict__ qkv,
                                                     unsigned short* __restrict__ vt,
                                                     float* __restrict__ newv) {
  __shared__ unsigned short T[32][136];
  const int st = blockIdx.x;           // 0..63
  const int kvh = blockIdx.y & 3, b = blockIdx.y >> 2;
  const int s0 = st * 32;
  const int t = threadIdx.x;
  const int ls = t >> 3;               // local s 0..31
  const int ch = (t & 7) * 2;          // 16B-chunk pair
  const unsigned short* src = qkv + (size_t)(b * 2048 + s0 + ls) * 3072 + 2560 + kvh * 128 + ch * 8;
  u16x8 a0 = *reinterpret_cast<const u16x8*>(src);
  u16x8 a1 = *reinterpret_cast<const u16x8*>(src + 8);
  *reinterpret_cast<u16x8*>(&T[ls][ch * 8])     = a0;
  *reinterpret_cast<u16x8*>(&T[ls][ch * 8 + 8]) = a1;
  float* nv = newv + (size_t)(b * 2048 + s0 + ls) * 512 + kvh * 128 + ch * 8;
  float4 f0, f1, f2, f3;
  f0.x = b2f(a0[0]); f0.y = b2f(a0[1]); f0.z = b2f(a0[2]); f0.w = b2f(a0[3]);
  f1.x = b2f(a0[4]); f1.y = b2f(a0[5]); f1.z = b2f(a0[6]); f1.w = b2f(a0[7]);
  f2.x = b2f(a1[0]); f2.y = b2f(a1[1]); f2.z = b2f(a1[2]); f2.w = b2f(a1[3]);
  f3.x = b2f(a1[4]); f3.y = b2f(a1[5]); f3.z = b2f(a1[6]); f3.w = b2f(a1[7]);
  reinterpret_cast<float4*>(nv)[0] = f0;
  reinterpret_cast<float4*>(nv)[1] = f1;
  reinterpret_cast<float4*>(nv)[2] = f2;
  reinterpret_cast<float4*>(nv)[3] = f3;
  __syncthreads();
  const int d = t >> 1, half = t & 1;
  unsigned short* dst = vt + ((size_t)(b * 4 + kvh) * 128 + d) * 2048 + s0 + half * 16;
  u16x8 o0, o1;
#pragma unroll
  for (int q = 0; q < 8; q++) {
    int slot = half * 16 + q;
    int kl = ((slot >> 2) & 1) * 16 + (slot >> 3) * 4 + (slot & 3);
    o0[q] = T[kl][d];
  }
#pragma unroll
  for (int q = 0; q < 8; q++) {
    int slot = half * 16 + 8 + q;
    int kl = ((slot >> 2) & 1) * 16 + (slot >> 3) * 4 + (slot & 3);
    o1[q] = T[kl][d];
  }
  reinterpret_cast<u16x8*>(dst)[0] = o0;
  reinterpret_cast<u16x8*>(dst)[1] = o1;
}

// ---------------- flash attention: block = (q-tile16, kvh, b), 4 waves = 4 heads
__global__ __launch_bounds__(256, 4) void attn_kernel(const unsigned short* __restrict__ qro,
                                                      const unsigned short* __restrict__ kro,
                                                      const unsigned short* __restrict__ vt,
                                                      unsigned short* __restrict__ out) {
  __shared__ unsigned short Ks[2][32 * 128];   // [kv][d], rows 256B, swizzled
  __shared__ unsigned short Vs[2][64 * 64];    // paired-d rows 128B, swizzled
  const int tid = threadIdx.x, lane = tid & 63, w = tid >> 6;
  const int kvhb = blockIdx.x & 7;             // XCD pin: same (kvh,b) -> same XCD
  const int kvh = kvhb & 3, b = kvhb >> 2;
  const int t = 127 - (blockIdx.x >> 3);       // heavy-first
  const int h = kvh * 4 + w;                   // wave = one q-head
  const int qbase = t * 16;
  const int fr = lane & 15, g = lane >> 4, fk = g * 8;
  const unsigned short* Kp = kro + (size_t)(b * 4 + kvh) * 2048 * 128;
  const unsigned short* Vtp = vt + (size_t)(b * 4 + kvh) * 128 * 2048;
  const unsigned short* Qp = qro + ((size_t)(b * 16 + h) * 2048 + qbase) * 128;

  bf16x8 qf[4];
#pragma unroll
  for (int kk = 0; kk < 4; kk++)
    qf[kk] = *reinterpret_cast<const bf16x8*>(Qp + fr * 128 + kk * 32 + fk);

  u16x8 onesu;
#pragma unroll
  for (int j = 0; j < 8; j++) onesu[j] = 0x3F80;  // bf16 1.0
  bf16x8 ones = __builtin_bit_cast(bf16x8, onesu);

  f32x4 o[8];
#pragma unroll
  for (int dt = 0; dt < 8; dt++) o[dt] = f32x4{0.f, 0.f, 0.f, 0.f};
  f32x4 dacc = f32x4{0.f, 0.f, 0.f, 0.f};
  const int qrow_s = qbase + fr;
  const int nfull = (qbase >= 31) ? ((qbase - 31) >> 5) + 1 : 0;
  const int niter = nfull + 1;

  const int krow = w * 8 + (lane >> 4);        // K stage rows (+j*4)
  const int kcol = lane & 15;
  const int vrow = w * 16 + (lane >> 3);       // V stage rows, paired-d (+j*8)
  const int vcol = lane & 7;

  auto stage = [&](int kv0, int buf) {
    unsigned short* Kb = &Ks[buf][0];
    unsigned short* Vb = &Vs[buf][0];
#pragma unroll
    for (int j = 0; j < 2; j++) {
      int r = krow + j * 4;
      glds16(Kp + (size_t)(kv0 + r) * 128 + ((kcol ^ (r & 7)) * 8),
             Kb + (w * 8 + j * 4) * 128);
    }
#pragma unroll
    for (int j = 0; j < 2; j++) {
      int r = vrow + j * 8;
      int u = vcol ^ (r & 7);
      int d = 2 * r + (u >> 2);
      glds16(Vtp + (size_t)d * 2048 + kv0 + (u & 3) * 8,
             Vb + (w * 16 + j * 8) * 64);
    }
  };

  auto step = [&](int kv0, bool mask, int buf) {
    const unsigned short* Kb = &Ks[buf][0];
    const unsigned short* Vb = &Vs[buf][0];
    f32x4 sc[2];
    sc[0] = sc[1] = f32x4{0.f, 0.f, 0.f, 0.f};
    __builtin_amdgcn_s_setprio(1);
#pragma unroll
    for (int kk = 0; kk < 4; kk++) {
      int blk = ((kk * 4 + g) ^ (fr & 7)) * 8;
      bf16x8 ka0 = *reinterpret_cast<const bf16x8*>(Kb + (fr +  0) * 128 + blk);
      bf16x8 ka1 = *reinterpret_cast<const bf16x8*>(Kb + (fr + 16) * 128 + blk);
      sc[0] = __builtin_amdgcn_mfma_f32_16x16x32_bf16(ka0, qf[kk], sc[0], 0, 0, 0);
      sc[1] = __builtin_amdgcn_mfma_f32_16x16x32_bf16(ka1, qf[kk], sc[1], 0, 0, 0);
    }
    __builtin_amdgcn_s_setprio(0);
#pragma unroll
    for (int s = 0; s < 2; s++)
#pragma unroll
      for (int r = 0; r < 4; r++) {
        float v = sc[s][r];
        if (mask && (kv0 + 16 * s + 4 * g + r > qrow_s)) v = -1e30f;
        sc[s][r] = __builtin_amdgcn_exp2f(v);
      }
    u16x8 pau;
#pragma unroll
    for (int j = 0; j < 4; j++) {
      pau[j]     = f2b(sc[0][j]);
      pau[4 + j] = f2b(sc[1][j]);
    }
    bf16x8 pa = __builtin_bit_cast(bf16x8, pau);
    dacc = __builtin_amdgcn_mfma_f32_16x16x32_bf16(pa, ones, dacc, 0, 0, 0);
    __builtin_amdgcn_s_setprio(1);
#pragma unroll
    for (int dt = 0; dt < 8; dt++) {
      int jr = dt * 8 + (fr >> 1);
      int c = ((fr & 1) * 4 + g) ^ (fr >> 1);
      bf16x8 vf = *reinterpret_cast<const bf16x8*>(Vb + jr * 64 + c * 8);
      o[dt] = __builtin_amdgcn_mfma_f32_16x16x32_bf16(pa, vf, o[dt], 0, 0, 0);
    }
    __builtin_amdgcn_s_setprio(0);
  };

  stage(0, 0);
  int buf = 0;
  for (int i = 0; i < niter; i++) {
    __syncthreads();                 // tile i staged; prior reads of buf^1 done
    if (i + 1 < niter) stage((i + 1) * 32, buf ^ 1);
    step(i * 32, i == nfull, buf);
    buf ^= 1;
  }

#pragma unroll
  for (int r = 0; r < 4; r++) {
    float inv = 1.0f / dacc[r];
    int qrow = qbase + g * 4 + r;
    size_t rowoff = ((size_t)b * 2048 + qrow) * 2048 + (size_t)h * 128;
#pragma unroll
    for (int dt = 0; dt < 8; dt++)
      out[rowoff + dt * 16 + fr] = f2b(o[dt][r] * inv);
  }
}

// ---------------- launch ---------------------------------------------------
extern "C" void kernel_launch(void* const* d_in, const int* in_sizes, int n_in,
                              void* d_out, int out_size, void* d_ws, size_t ws_size,
                              hipStream_t stream) {
  const float* x  = (const float*)d_in[0];
  const float* wq = (const float*)d_in[1];
  const float* wk = (const float*)d_in[2];
  const float* wv = (const float*)d_in[3];
  const float* wo = (const float*)d_in[4];
  const float* freqs = (const float*)d_in[5];

  char* ws = (char*)d_ws;
  unsigned short* xb    = (unsigned short*)(ws);             // 16 MB, reused as attn out
  unsigned short* attn  = xb;
  unsigned short* wqkvb = (unsigned short*)(ws + 16777216);  // [3072][2048] bf16
  unsigned short* wob   = (unsigned short*)(ws + 29360128);
  unsigned short* qkv   = (unsigned short*)(ws + 37748736);  // [4096][3072] bf16
  unsigned short* qro   = (unsigned short*)(ws + 62914560);
  unsigned short* kro   = (unsigned short*)(ws + 79691776);
  unsigned short* vt    = (unsigned short*)(ws + 83886080);

  float* out_o = (float*)d_out;
  float* out_k = (float*)d_out + 8388608;
  float* out_v = (float*)d_out + 10485760;

  cvt_fused<<<9216, 256, 0, stream>>>(x, wq, wk, wv, wo, xb, wqkvb, wob);

  // QKV: 256x256 tiles -> 16 x 12 = 192 blocks
  gemm_q<0><<<192, 512, 0, stream>>>(xb, wqkvb, qkv, 3072, 2048, 12);

  rope_kernel<<<20480, 256, 0, stream>>>(qkv, freqs, qro, kro, out_k);
  vtrans_kernel<<<dim3(64, 8), 256, 0, stream>>>(qkv, vt, out_v);

  attn_kernel<<<1024, 256, 0, stream>>>(qro, kro, vt, attn);

  // O: 256x256 tiles -> 16 x 8 = 128 blocks
  gemm_q<1><<<128, 512, 0, stream>>>(attn, wob, out_o, 2048, 2048, 8);
}

// Round 13
// 214.120 us; speedup vs baseline: 1.0104x; 1.0104x over previous
//
#include <hip/hip_runtime.h>
#include <hip/hip_bf16.h>

#define NH 16
#define NKV 4
#define HD 128
// ATT_SCALE * log2(e): Q pre-scaled so P = exp2(S_mfma)
#define QSCALE 0.1275174272f

using bf16x8 = __attribute__((ext_vector_type(8))) __bf16;
using f32x4  = __attribute__((ext_vector_type(4))) float;
using u16x8  = __attribute__((ext_vector_type(8))) unsigned short;
using u16x2  = __attribute__((ext_vector_type(2))) unsigned short;

__device__ __forceinline__ unsigned short f2b(float f) {
  __hip_bfloat16 h = __float2bfloat16(f);
  return __builtin_bit_cast(unsigned short, h);
}
__device__ __forceinline__ float b2f(unsigned short u) {
  unsigned int v = ((unsigned int)u) << 16;
  return __builtin_bit_cast(float, v);
}

__device__ __forceinline__ void glds16(const unsigned short* g, unsigned short* l) {
  __builtin_amdgcn_global_load_lds(
      (const __attribute__((address_space(1))) unsigned int*)(const void*)g,
      (__attribute__((address_space(3))) unsigned int*)(void*)l, 16, 0, 0);
}

// ---------------- fused fp32 -> bf16 conversion (8 elems/thread) ----------
__global__ __launch_bounds__(256) void cvt_fused(const float* __restrict__ x,
                                                 const float* __restrict__ wq,
                                                 const float* __restrict__ wk,
                                                 const float* __restrict__ wv,
                                                 const float* __restrict__ wo,
                                                 unsigned short* __restrict__ xb,
                                                 unsigned short* __restrict__ wqkvb,
                                                 unsigned short* __restrict__ wob) {
  int i = blockIdx.x * 256 + threadIdx.x;
  const float* src;
  unsigned short* dst;
  int off;
  if (i < 1048576)      { src = x;  dst = xb;              off = i; }
  else if (i < 1572864) { src = wq; dst = wqkvb;           off = i - 1048576; }
  else if (i < 1703936) { src = wk; dst = wqkvb + 4194304; off = i - 1572864; }
  else if (i < 1835008) { src = wv; dst = wqkvb + 5242880; off = i - 1703936; }
  else                  { src = wo; dst = wob;             off = i - 1835008; }
  const float4* s4 = reinterpret_cast<const float4*>(src) + (size_t)off * 2;
  float4 v0 = s4[0], v1 = s4[1];
  u16x8 o;
  o[0] = f2b(v0.x); o[1] = f2b(v0.y); o[2] = f2b(v0.z); o[3] = f2b(v0.w);
  o[4] = f2b(v1.x); o[5] = f2b(v1.y); o[6] = f2b(v1.z); o[7] = f2b(v1.w);
  reinterpret_cast<u16x8*>(dst)[off] = o;
}

// ---------------- GEMM, full-chip single-round (R11, best measured) -------
// C[M,N] = A[M,K]*B[N,K]^T. BM=128, BN in {384,256}, BK=32. 512 thr = 8
// waves (2M x 4N), wave out = 64 x BN/4 (acc[4][BF]). 3 rotating K-tile
// buffers (WAR-free by construction). 2 phases per K-tile:
// {ds_read frags | stage part of t+2 | barrier | lgkmcnt(0) | MFMA | barrier}
// Boundary: vmcnt(AL+BL) keeps tile t+2's loads in flight (T4), drains t+1.
// LDS line = 128B = 2 K-rows x 8 16B chunks, phys chunk = cl ^ (R&7),
// inverse on glds source (T2, 0 conflicts measured R6-R11).
template<int CF32, int BN>
__global__ __launch_bounds__(512, 1) void gemm_full(const unsigned short* __restrict__ A,
                                                    const unsigned short* __restrict__ B,
                                                    void* __restrict__ C,
                                                    int N, int K, int nbx) {
  constexpr int BM = 128;
  constexpr int AF = 4;
  constexpr int BF = BN / 64;
  constexpr int BH = BF / 2;
  constexpr int AL = 1;
  constexpr int BL = BN / 128;
  __shared__ unsigned short As[3][BM * 32];
  __shared__ unsigned short Bs[3][BN * 32];
  const int tid = threadIdx.x, lane = tid & 63;
  const int wid = tid >> 6, wm = wid >> 2, wn = wid & 3;
  const int cpx = gridDim.x >> 3;
  const int wgid = (blockIdx.x & 7) * cpx + (blockIdx.x >> 3);
  const int bx = wgid % nbx, by = wgid / nbx;
  const int row0 = by * BM, col0 = bx * BN;
  const int fr = lane & 15, g = lane >> 4;
  const int NT = K >> 5;

  size_t offA;
  {
    int cid = tid, R = cid >> 3, phys = cid & 7, cl = phys ^ (R & 7);
    offA = (size_t)(row0 + 2 * R + (cl >> 2)) * K + (cl & 3) * 8;
  }
  size_t offB[BL];
#pragma unroll
  for (int l = 0; l < BL; l++) {
    int cid = tid + l * 512, R = cid >> 3, phys = cid & 7, cl = phys ^ (R & 7);
    offB[l] = (size_t)(col0 + 2 * R + (cl >> 2)) * K + (cl & 3) * 8;
  }

  auto stage_p0 = [&](int t, int sb) {
    int k0 = t * 32;
    glds16(A + offA + k0, &As[sb][tid * 8]);
    glds16(B + offB[0] + k0, &Bs[sb][tid * 8]);
  };
  auto stage_p1 = [&](int t, int sb) {
    int k0 = t * 32;
#pragma unroll
    for (int l = 1; l < BL; l++)
      glds16(B + offB[l] + k0, &Bs[sb][(tid + l * 512) * 8]);
  };

  auto ldfrag = [&](const unsigned short* buf, int row) {
    int R = row >> 1;
    int phys = ((((row & 1) << 2) | g) ^ (R & 7));
    return *reinterpret_cast<const bf16x8*>(&buf[R * 64 + phys * 8]);
  };

  f32x4 acc[AF][BF];
#pragma unroll
  for (int i = 0; i < AF; i++)
#pragma unroll
    for (int j = 0; j < BF; j++) acc[i][j] = f32x4{0.f, 0.f, 0.f, 0.f};

  stage_p0(0, 0); stage_p1(0, 0);
  stage_p0(1, 1); stage_p1(1, 1);
  if constexpr (AL + BL == 4) asm volatile("s_waitcnt vmcnt(4)" ::: "memory");
  else                        asm volatile("s_waitcnt vmcnt(3)" ::: "memory");
  __builtin_amdgcn_s_barrier();
  __builtin_amdgcn_sched_barrier(0);

  int rb = 0, sb = 2;
#pragma unroll 1
  for (int t = 0; t < NT; ++t) {
    const unsigned short* Ar = &As[rb][0];
    const unsigned short* Br = &Bs[rb][0];

    bf16x8 af[AF], bfr[BF];
#pragma unroll
    for (int mf = 0; mf < AF; mf++) af[mf] = ldfrag(Ar, wm * 64 + mf * 16 + fr);
#pragma unroll
    for (int nf = 0; nf < BH; nf++) bfr[nf] = ldfrag(Br, wn * (BN / 4) + nf * 16 + fr);
    if (t + 2 < NT) stage_p0(t + 2, sb);
    __builtin_amdgcn_s_barrier();
    asm volatile("s_waitcnt lgkmcnt(0)" ::: "memory");
    __builtin_amdgcn_sched_barrier(0);
    __builtin_amdgcn_s_setprio(1);
#pragma unroll
    for (int mf = 0; mf < AF; mf++)
#pragma unroll
      for (int nf = 0; nf < BH; nf++)
        acc[mf][nf] = __builtin_amdgcn_mfma_f32_16x16x32_bf16(af[mf], bfr[nf], acc[mf][nf], 0, 0, 0);
    __builtin_amdgcn_s_setprio(0);
    __builtin_amdgcn_sched_barrier(0);
    __builtin_amdgcn_s_barrier();

#pragma unroll
    for (int nf = BH; nf < BF; nf++) bfr[nf] = ldfrag(Br, wn * (BN / 4) + nf * 16 + fr);
    if (t + 2 < NT) stage_p1(t + 2, sb);
    __builtin_amdgcn_s_barrier();
    asm volatile("s_waitcnt lgkmcnt(0)" ::: "memory");
    __builtin_amdgcn_sched_barrier(0);
    __builtin_amdgcn_s_setprio(1);
#pragma unroll
    for (int mf = 0; mf < AF; mf++)
#pragma unroll
      for (int nf = BH; nf < BF; nf++)
        acc[mf][nf] = __builtin_amdgcn_mfma_f32_16x16x32_bf16(af[mf], bfr[nf], acc[mf][nf], 0, 0, 0);
    __builtin_amdgcn_s_setprio(0);
    __builtin_amdgcn_sched_barrier(0);

    if (t + 1 < NT) {
      if (t + 2 < NT) {
        if constexpr (AL + BL == 4) asm volatile("s_waitcnt vmcnt(4)" ::: "memory");
        else                        asm volatile("s_waitcnt vmcnt(3)" ::: "memory");
      } else {
        asm volatile("s_waitcnt vmcnt(0)" ::: "memory");
      }
      __builtin_amdgcn_s_barrier();
      __builtin_amdgcn_sched_barrier(0);
    }
    rb = rb == 2 ? 0 : rb + 1;
    sb = sb == 2 ? 0 : sb + 1;
  }

#pragma unroll
  for (int i = 0; i < AF; i++) {
#pragma unroll
    for (int j = 0; j < BF; j++) {
      int rbase = row0 + wm * 64 + i * 16 + g * 4;
      int cb = col0 + wn * (BN / 4) + j * 16 + fr;
#pragma unroll
      for (int r = 0; r < 4; r++) {
        if (CF32)
          reinterpret_cast<float*>(C)[(size_t)(rbase + r) * N + cb] = acc[i][j][r];
        else
          reinterpret_cast<unsigned short*>(C)[(size_t)(rbase + r) * N + cb] = f2b(acc[i][j][r]);
      }
    }
  }
}

// ---------------- RoPE (reads fused qkv [4096][3072]) ---------------------
__global__ __launch_bounds__(256) void rope_kernel(const unsigned short* __restrict__ qkv,
                                                   const float* __restrict__ freqs,
                                                   unsigned short* __restrict__ qro,
                                                   unsigned short* __restrict__ kro,
                                                   float* __restrict__ newk) {
  const int NQ = 4096 * 16 * 64;
  const int NK = 4096 * 4 * 64;
  int idx = blockIdx.x * 256 + threadIdx.x;
  if (idx >= NQ + NK) return;
  if (idx < NQ) {
    int i = idx & 63;
    int h = (idx >> 6) & 15;
    int row = idx >> 10;             // b*2048 + s
    int s = row & 2047, b = row >> 11;
    float f = freqs[s * 64 + i];
    float c = cosf(f), sn = sinf(f);
    u16x2 xv = *reinterpret_cast<const u16x2*>(qkv + (size_t)row * 3072 + h * 128 + 2 * i);
    float x1 = b2f(xv.x), x2 = b2f(xv.y);
    float r1 = (x1 * c - x2 * sn) * QSCALE;
    float r2 = (x1 * sn + x2 * c) * QSCALE;
    u16x2 o; o.x = f2b(r1); o.y = f2b(r2);
    *reinterpret_cast<u16x2*>(qro + ((size_t)(b * 16 + h) * 2048 + s) * 128 + 2 * i) = o;
  } else {
    idx -= NQ;
    int i = idx & 63;
    int h = (idx >> 6) & 3;
    int row = idx >> 8;
    int s = row & 2047, b = row >> 11;
    float f = freqs[s * 64 + i];
    float c = cosf(f), sn = sinf(f);
    u16x2 xv = *reinterpret_cast<const u16x2*>(qkv + (size_t)row * 3072 + 2048 + h * 128 + 2 * i);
    float x1 = b2f(xv.x), x2 = b2f(xv.y);
    float r1 = x1 * c - x2 * sn;
    float r2 = x1 * sn + x2 * c;
    u16x2 o; o.x = f2b(r1); o.y = f2b(r2);
    *reinterpret_cast<u16x2*>(kro + ((size_t)(b * 4 + h) * 2048 + s) * 128 + 2 * i) = o;
    float2 of; of.x = r1; of.y = r2;
    *reinterpret_cast<float2*>(newk + (size_t)row * 512 + h * 128 + 2 * i) = of;
  }
}

// ---------------- V: LDS-tiled transpose -> vt[B][KVH][D][S] (slot-permuted)
__global__ __launch_bounds__(256) void vtrans_kernel(const unsigned short* __restrict__ qkv,
                                                     unsigned short* __restrict__ vt,
                                                     float* __restrict__ newv) {
  __shared__ unsigned short T[32][136];
  const int st = blockIdx.x;           // 0..63
  const int kvh = blockIdx.y & 3, b = blockIdx.y >> 2;
  const int s0 = st * 32;
  const int t = threadIdx.x;
  const int ls = t >> 3;               // local s 0..31
  const int ch = (t & 7) * 2;          // 16B-chunk pair
  const unsigned short* src = qkv + (size_t)(b * 2048 + s0 + ls) * 3072 + 2560 + kvh * 128 + ch * 8;
  u16x8 a0 = *reinterpret_cast<const u16x8*>(src);
  u16x8 a1 = *reinterpret_cast<const u16x8*>(src + 8);
  *reinterpret_cast<u16x8*>(&T[ls][ch * 8])     = a0;
  *reinterpret_cast<u16x8*>(&T[ls][ch * 8 + 8]) = a1;
  float* nv = newv + (size_t)(b * 2048 + s0 + ls) * 512 + kvh * 128 + ch * 8;
  float4 f0, f1, f2, f3;
  f0.x = b2f(a0[0]); f0.y = b2f(a0[1]); f0.z = b2f(a0[2]); f0.w = b2f(a0[3]);
  f1.x = b2f(a0[4]); f1.y = b2f(a0[5]); f1.z = b2f(a0[6]); f1.w = b2f(a0[7]);
  f2.x = b2f(a1[0]); f2.y = b2f(a1[1]); f2.z = b2f(a1[2]); f2.w = b2f(a1[3]);
  f3.x = b2f(a1[4]); f3.y = b2f(a1[5]); f3.z = b2f(a1[6]); f3.w = b2f(a1[7]);
  reinterpret_cast<float4*>(nv)[0] = f0;
  reinterpret_cast<float4*>(nv)[1] = f1;
  reinterpret_cast<float4*>(nv)[2] = f2;
  reinterpret_cast<float4*>(nv)[3] = f3;
  __syncthreads();
  const int d = t >> 1, half = t & 1;
  unsigned short* dst = vt + ((size_t)(b * 4 + kvh) * 128 + d) * 2048 + s0 + half * 16;
  u16x8 o0, o1;
#pragma unroll
  for (int q = 0; q < 8; q++) {
    int slot = half * 16 + q;
    int kl = ((slot >> 2) & 1) * 16 + (slot >> 3) * 4 + (slot & 3);
    o0[q] = T[kl][d];
  }
#pragma unroll
  for (int q = 0; q < 8; q++) {
    int slot = half * 16 + 8 + q;
    int kl = ((slot >> 2) & 1) * 16 + (slot >> 3) * 4 + (slot & 3);
    o1[q] = T[kl][d];
  }
  reinterpret_cast<u16x8*>(dst)[0] = o0;
  reinterpret_cast<u16x8*>(dst)[1] = o1;
}

// ---------------- flash attention: block = (q-tile32, kvh, b), 4 waves = 4 heads
// Each wave owns 32 q-rows (two Q B-frag sets) -> per 32-KV iter: 16 QK +
// 16 PV + 2 dacc MFMA sharing ONE set of 16 ds_reads; 2 independent
// softmax chains per wave (ILP). Half the iterations/barriers of q-tile16.
__global__ __launch_bounds__(256, 2) void attn_kernel(const unsigned short* __restrict__ qro,
                                                      const unsigned short* __restrict__ kro,
                                                      const unsigned short* __restrict__ vt,
                                                      unsigned short* __restrict__ out) {
  __shared__ unsigned short Ks[2][32 * 128];   // [kv][d], rows 256B, swizzled
  __shared__ unsigned short Vs[2][64 * 64];    // paired-d rows 128B, swizzled
  const int tid = threadIdx.x, lane = tid & 63, w = tid >> 6;
  const int kvhb = blockIdx.x & 7;             // XCD pin: same (kvh,b) -> same XCD
  const int kvh = kvhb & 3, b = kvhb >> 2;
  const int t = 63 - (blockIdx.x >> 3);        // 0..63, heavy-first
  const int h = kvh * 4 + w;                   // wave = one q-head
  const int qbase = t * 32;
  const int fr = lane & 15, g = lane >> 4, fk = g * 8;
  const unsigned short* Kp = kro + (size_t)(b * 4 + kvh) * 2048 * 128;
  const unsigned short* Vtp = vt + (size_t)(b * 4 + kvh) * 128 * 2048;
  const unsigned short* Qp = qro + ((size_t)(b * 16 + h) * 2048 + qbase) * 128;

  bf16x8 qf0[4], qf1[4];
#pragma unroll
  for (int kk = 0; kk < 4; kk++) {
    qf0[kk] = *reinterpret_cast<const bf16x8*>(Qp + fr * 128 + kk * 32 + fk);
    qf1[kk] = *reinterpret_cast<const bf16x8*>(Qp + (16 + fr) * 128 + kk * 32 + fk);
  }

  u16x8 onesu;
#pragma unroll
  for (int j = 0; j < 8; j++) onesu[j] = 0x3F80;  // bf16 1.0
  bf16x8 ones = __builtin_bit_cast(bf16x8, onesu);

  f32x4 o0[8], o1[8];
#pragma unroll
  for (int dt = 0; dt < 8; dt++) { o0[dt] = f32x4{0.f, 0.f, 0.f, 0.f}; o1[dt] = f32x4{0.f, 0.f, 0.f, 0.f}; }
  f32x4 dacc0 = f32x4{0.f, 0.f, 0.f, 0.f};
  f32x4 dacc1 = f32x4{0.f, 0.f, 0.f, 0.f};
  const int qrow0 = qbase + fr, qrow1 = qbase + 16 + fr;
  const int niter = t + 1;

  const int krow = w * 8 + (lane >> 4);        // K stage rows (+j*4)
  const int kcol = lane & 15;
  const int vrow = w * 16 + (lane >> 3);       // V stage rows, paired-d (+j*8)
  const int vcol = lane & 7;

  auto stage = [&](int kv0, int buf) {
    unsigned short* Kb = &Ks[buf][0];
    unsigned short* Vb = &Vs[buf][0];
#pragma unroll
    for (int j = 0; j < 2; j++) {
      int r = krow + j * 4;
      glds16(Kp + (size_t)(kv0 + r) * 128 + ((kcol ^ (r & 7)) * 8),
             Kb + (w * 8 + j * 4) * 128);
    }
#pragma unroll
    for (int j = 0; j < 2; j++) {
      int r = vrow + j * 8;
      int u = vcol ^ (r & 7);
      int d = 2 * r + (u >> 2);
      glds16(Vtp + (size_t)d * 2048 + kv0 + (u & 3) * 8,
             Vb + (w * 16 + j * 8) * 64);
    }
  };

  auto step = [&](int kv0, bool mask, int buf) {
    const unsigned short* Kb = &Ks[buf][0];
    const unsigned short* Vb = &Vs[buf][0];
    f32x4 sA[2], sB[2];                        // set0 / set1, kv-halves
    sA[0] = sA[1] = f32x4{0.f, 0.f, 0.f, 0.f};
    sB[0] = sB[1] = f32x4{0.f, 0.f, 0.f, 0.f};
    __builtin_amdgcn_s_setprio(1);
#pragma unroll
    for (int kk = 0; kk < 4; kk++) {
      int blk = ((kk * 4 + g) ^ (fr & 7)) * 8;
      bf16x8 ka0 = *reinterpret_cast<const bf16x8*>(Kb + (fr +  0) * 128 + blk);
      bf16x8 ka1 = *reinterpret_cast<const bf16x8*>(Kb + (fr + 16) * 128 + blk);
      sA[0] = __builtin_amdgcn_mfma_f32_16x16x32_bf16(ka0, qf0[kk], sA[0], 0, 0, 0);
      sB[0] = __builtin_amdgcn_mfma_f32_16x16x32_bf16(ka0, qf1[kk], sB[0], 0, 0, 0);
      sA[1] = __builtin_amdgcn_mfma_f32_16x16x32_bf16(ka1, qf0[kk], sA[1], 0, 0, 0);
      sB[1] = __builtin_amdgcn_mfma_f32_16x16x32_bf16(ka1, qf1[kk], sB[1], 0, 0, 0);
    }
    __builtin_amdgcn_s_setprio(0);
#pragma unroll
    for (int hh = 0; hh < 2; hh++)
#pragma unroll
      for (int r = 0; r < 4; r++) {
        int kvidx = kv0 + 16 * hh + 4 * g + r;
        float vA = sA[hh][r];
        float vB = sB[hh][r];
        if (mask && (kvidx > qrow0)) vA = -1e30f;
        if (mask && (kvidx > qrow1)) vB = -1e30f;
        sA[hh][r] = __builtin_amdgcn_exp2f(vA);
        sB[hh][r] = __builtin_amdgcn_exp2f(vB);
      }
    u16x8 pau, pbu;
#pragma unroll
    for (int j = 0; j < 4; j++) {
      pau[j]     = f2b(sA[0][j]);
      pau[4 + j] = f2b(sA[1][j]);
      pbu[j]     = f2b(sB[0][j]);
      pbu[4 + j] = f2b(sB[1][j]);
    }
    bf16x8 pa = __builtin_bit_cast(bf16x8, pau);
    bf16x8 pb = __builtin_bit_cast(bf16x8, pbu);
    dacc0 = __builtin_amdgcn_mfma_f32_16x16x32_bf16(pa, ones, dacc0, 0, 0, 0);
    dacc1 = __builtin_amdgcn_mfma_f32_16x16x32_bf16(pb, ones, dacc1, 0, 0, 0);
    __builtin_amdgcn_s_setprio(1);
#pragma unroll
    for (int dt = 0; dt < 8; dt++) {
      int jr = dt * 8 + (fr >> 1);
      int c = ((fr & 1) * 4 + g) ^ (fr >> 1);
      bf16x8 vf = *reinterpret_cast<const bf16x8*>(Vb + jr * 64 + c * 8);
      o0[dt] = __builtin_amdgcn_mfma_f32_16x16x32_bf16(pa, vf, o0[dt], 0, 0, 0);
      o1[dt] = __builtin_amdgcn_mfma_f32_16x16x32_bf16(pb, vf, o1[dt], 0, 0, 0);
    }
    __builtin_amdgcn_s_setprio(0);
  };

  stage(0, 0);
  int buf = 0;
  for (int i = 0; i < niter; i++) {
    __syncthreads();                 // tile i staged; prior reads of buf^1 done
    if (i + 1 < niter) stage((i + 1) * 32, buf ^ 1);
    step(i * 32, i == niter - 1, buf);
    buf ^= 1;
  }

#pragma unroll
  for (int r = 0; r < 4; r++) {
    float inv0 = 1.0f / dacc0[r];
    float inv1 = 1.0f / dacc1[r];
    int q0 = qbase + g * 4 + r;
    int q1 = qbase + 16 + g * 4 + r;
    size_t ro0 = ((size_t)b * 2048 + q0) * 2048 + (size_t)h * 128;
    size_t ro1 = ((size_t)b * 2048 + q1) * 2048 + (size_t)h * 128;
#pragma unroll
    for (int dt = 0; dt < 8; dt++) {
      out[ro0 + dt * 16 + fr] = f2b(o0[dt][r] * inv0);
      out[ro1 + dt * 16 + fr] = f2b(o1[dt][r] * inv1);
    }
  }
}

// ---------------- launch ---------------------------------------------------
extern "C" void kernel_launch(void* const* d_in, const int* in_sizes, int n_in,
                              void* d_out, int out_size, void* d_ws, size_t ws_size,
                              hipStream_t stream) {
  const float* x  = (const float*)d_in[0];
  const float* wq = (const float*)d_in[1];
  const float* wk = (const float*)d_in[2];
  const float* wv = (const float*)d_in[3];
  const float* wo = (const float*)d_in[4];
  const float* freqs = (const float*)d_in[5];

  char* ws = (char*)d_ws;
  unsigned short* xb    = (unsigned short*)(ws);             // 16 MB, reused as attn out
  unsigned short* attn  = xb;
  unsigned short* wqkvb = (unsigned short*)(ws + 16777216);  // [3072][2048] bf16
  unsigned short* wob   = (unsigned short*)(ws + 29360128);
  unsigned short* qkv   = (unsigned short*)(ws + 37748736);  // [4096][3072] bf16
  unsigned short* qro   = (unsigned short*)(ws + 62914560);
  unsigned short* kro   = (unsigned short*)(ws + 79691776);
  unsigned short* vt    = (unsigned short*)(ws + 83886080);

  float* out_o = (float*)d_out;
  float* out_k = (float*)d_out + 8388608;
  float* out_v = (float*)d_out + 10485760;

  cvt_fused<<<9216, 256, 0, stream>>>(x, wq, wk, wv, wo, xb, wqkvb, wob);

  // QKV: BM=128 x BN=384 -> grid 32x8 = 256 blocks = full chip, 1 round
  gemm_full<0, 384><<<256, 512, 0, stream>>>(xb, wqkvb, qkv, 3072, 2048, 8);

  rope_kernel<<<20480, 256, 0, stream>>>(qkv, freqs, qro, kro, out_k);
  vtrans_kernel<<<dim3(64, 8), 256, 0, stream>>>(qkv, vt, out_v);

  // attn: 64 q-tiles of 32 rows x 8 (kvh,b) = 512 blocks
  attn_kernel<<<512, 256, 0, stream>>>(qro, kro, vt, attn);

  // O: BM=128 x BN=256 -> grid 32x8 = 256 blocks = full chip, 1 round
  gemm_full<1, 256><<<256, 512, 0, stream>>>(attn, wob, out_o, 2048, 2048, 8);
}

// Round 14
// 195.303 us; speedup vs baseline: 1.1078x; 1.0964x over previous
//
#include <hip/hip_runtime.h>
#include <hip/hip_bf16.h>

#define NH 16
#define NKV 4
#define HD 128
// ATT_SCALE * log2(e): Q pre-scaled so P = exp2(S_mfma)
#define QSCALE 0.1275174272f

using bf16x8 = __attribute__((ext_vector_type(8))) __bf16;
using f32x4  = __attribute__((ext_vector_type(4))) float;
using u16x8  = __attribute__((ext_vector_type(8))) unsigned short;
using u16x4  = __attribute__((ext_vector_type(4))) unsigned short;
using u16x2  = __attribute__((ext_vector_type(2))) unsigned short;

__device__ __forceinline__ unsigned short f2b(float f) {
  __hip_bfloat16 h = __float2bfloat16(f);
  return __builtin_bit_cast(unsigned short, h);
}
__device__ __forceinline__ float b2f(unsigned short u) {
  unsigned int v = ((unsigned int)u) << 16;
  return __builtin_bit_cast(float, v);
}

__device__ __forceinline__ void glds16(const unsigned short* g, unsigned short* l) {
  __builtin_amdgcn_global_load_lds(
      (const __attribute__((address_space(1))) unsigned int*)(const void*)g,
      (__attribute__((address_space(3))) unsigned int*)(void*)l, 16, 0, 0);
}

// ---------------- fused fp32 -> bf16 conversion + cos/sin table -----------
__global__ __launch_bounds__(256) void cvt_fused(const float* __restrict__ x,
                                                 const float* __restrict__ wq,
                                                 const float* __restrict__ wk,
                                                 const float* __restrict__ wv,
                                                 const float* __restrict__ wo,
                                                 const float* __restrict__ freqs,
                                                 unsigned short* __restrict__ xb,
                                                 unsigned short* __restrict__ wqkvb,
                                                 unsigned short* __restrict__ wob,
                                                 float2* __restrict__ cs_tab) {
  int i = blockIdx.x * 256 + threadIdx.x;
  if (i >= 2359296) {                // cos/sin table: 2048*64 angles
    int k = i - 2359296;
    float f = freqs[k];
    float2 cs; cs.x = cosf(f); cs.y = sinf(f);
    cs_tab[k] = cs;
    return;
  }
  const float* src;
  unsigned short* dst;
  int off;
  if (i < 1048576)      { src = x;  dst = xb;              off = i; }
  else if (i < 1572864) { src = wq; dst = wqkvb;           off = i - 1048576; }
  else if (i < 1703936) { src = wk; dst = wqkvb + 4194304; off = i - 1572864; }
  else if (i < 1835008) { src = wv; dst = wqkvb + 5242880; off = i - 1703936; }
  else                  { src = wo; dst = wob;             off = i - 1835008; }
  const float4* s4 = reinterpret_cast<const float4*>(src) + (size_t)off * 2;
  float4 v0 = s4[0], v1 = s4[1];
  u16x8 o;
  o[0] = f2b(v0.x); o[1] = f2b(v0.y); o[2] = f2b(v0.z); o[3] = f2b(v0.w);
  o[4] = f2b(v1.x); o[5] = f2b(v1.y); o[6] = f2b(v1.z); o[7] = f2b(v1.w);
  reinterpret_cast<u16x8*>(dst)[off] = o;
}

// ---------------- QKV GEMM with fused RoPE/V-transpose epilogue -----------
// Main loop = R11's gemm_full<_,384> (best measured). Epilogue writes
// qro (RoPE*QSCALE), kro+newk (RoPE), vt (slot-permuted transpose)+newv
// directly from f32 accumulators. RoPE pair (d, d^1) lives in lanes
// (fr, fr^1) -> one shfl_xor + 2 FMA with float2 cos/sin table.
// V: 4 acc rows -> 4 consecutive vt slots (kl%4==0) -> one 8B store.
__global__ __launch_bounds__(512, 1) void gemm_qkv(const unsigned short* __restrict__ A,
                                                   const unsigned short* __restrict__ B,
                                                   const float2* __restrict__ cs_tab,
                                                   unsigned short* __restrict__ qro,
                                                   unsigned short* __restrict__ kro,
                                                   unsigned short* __restrict__ vt,
                                                   float* __restrict__ newk,
                                                   float* __restrict__ newv,
                                                   int K) {
  constexpr int BN = 384;
  constexpr int AF = 4, BF = 6, BH = 3, BL = 3;
  __shared__ unsigned short As[3][128 * 32];
  __shared__ unsigned short Bs[3][BN * 32];
  const int tid = threadIdx.x, lane = tid & 63;
  const int wid = tid >> 6, wm = wid >> 2, wn = wid & 3;
  const int cpx = gridDim.x >> 3;
  const int wgid = (blockIdx.x & 7) * cpx + (blockIdx.x >> 3);
  const int bx = wgid % 8, by = wgid / 8;
  const int row0 = by * 128, col0 = bx * BN;
  const int fr = lane & 15, g = lane >> 4;
  const int NT = K >> 5;

  size_t offA;
  {
    int cid = tid, R = cid >> 3, phys = cid & 7, cl = phys ^ (R & 7);
    offA = (size_t)(row0 + 2 * R + (cl >> 2)) * K + (cl & 3) * 8;
  }
  size_t offB[BL];
#pragma unroll
  for (int l = 0; l < BL; l++) {
    int cid = tid + l * 512, R = cid >> 3, phys = cid & 7, cl = phys ^ (R & 7);
    offB[l] = (size_t)(col0 + 2 * R + (cl >> 2)) * K + (cl & 3) * 8;
  }

  auto stage_p0 = [&](int t, int sb) {
    int k0 = t * 32;
    glds16(A + offA + k0, &As[sb][tid * 8]);
    glds16(B + offB[0] + k0, &Bs[sb][tid * 8]);
  };
  auto stage_p1 = [&](int t, int sb) {
    int k0 = t * 32;
#pragma unroll
    for (int l = 1; l < BL; l++)
      glds16(B + offB[l] + k0, &Bs[sb][(tid + l * 512) * 8]);
  };

  auto ldfrag = [&](const unsigned short* buf, int row) {
    int R = row >> 1;
    int phys = ((((row & 1) << 2) | g) ^ (R & 7));
    return *reinterpret_cast<const bf16x8*>(&buf[R * 64 + phys * 8]);
  };

  f32x4 acc[AF][BF];
#pragma unroll
  for (int i = 0; i < AF; i++)
#pragma unroll
    for (int j = 0; j < BF; j++) acc[i][j] = f32x4{0.f, 0.f, 0.f, 0.f};

  stage_p0(0, 0); stage_p1(0, 0);
  stage_p0(1, 1); stage_p1(1, 1);
  asm volatile("s_waitcnt vmcnt(4)" ::: "memory");
  __builtin_amdgcn_s_barrier();
  __builtin_amdgcn_sched_barrier(0);

  int rb = 0, sb = 2;
#pragma unroll 1
  for (int t = 0; t < NT; ++t) {
    const unsigned short* Ar = &As[rb][0];
    const unsigned short* Br = &Bs[rb][0];

    bf16x8 af[AF], bfr[BF];
#pragma unroll
    for (int mf = 0; mf < AF; mf++) af[mf] = ldfrag(Ar, wm * 64 + mf * 16 + fr);
#pragma unroll
    for (int nf = 0; nf < BH; nf++) bfr[nf] = ldfrag(Br, wn * 96 + nf * 16 + fr);
    if (t + 2 < NT) stage_p0(t + 2, sb);
    __builtin_amdgcn_s_barrier();
    asm volatile("s_waitcnt lgkmcnt(0)" ::: "memory");
    __builtin_amdgcn_sched_barrier(0);
    __builtin_amdgcn_s_setprio(1);
#pragma unroll
    for (int mf = 0; mf < AF; mf++)
#pragma unroll
      for (int nf = 0; nf < BH; nf++)
        acc[mf][nf] = __builtin_amdgcn_mfma_f32_16x16x32_bf16(af[mf], bfr[nf], acc[mf][nf], 0, 0, 0);
    __builtin_amdgcn_s_setprio(0);
    __builtin_amdgcn_sched_barrier(0);
    __builtin_amdgcn_s_barrier();

#pragma unroll
    for (int nf = BH; nf < BF; nf++) bfr[nf] = ldfrag(Br, wn * 96 + nf * 16 + fr);
    if (t + 2 < NT) stage_p1(t + 2, sb);
    __builtin_amdgcn_s_barrier();
    asm volatile("s_waitcnt lgkmcnt(0)" ::: "memory");
    __builtin_amdgcn_sched_barrier(0);
    __builtin_amdgcn_s_setprio(1);
#pragma unroll
    for (int mf = 0; mf < AF; mf++)
#pragma unroll
      for (int nf = BH; nf < BF; nf++)
        acc[mf][nf] = __builtin_amdgcn_mfma_f32_16x16x32_bf16(af[mf], bfr[nf], acc[mf][nf], 0, 0, 0);
    __builtin_amdgcn_s_setprio(0);
    __builtin_amdgcn_sched_barrier(0);

    if (t + 1 < NT) {
      if (t + 2 < NT) asm volatile("s_waitcnt vmcnt(4)" ::: "memory");
      else            asm volatile("s_waitcnt vmcnt(0)" ::: "memory");
      __builtin_amdgcn_s_barrier();
      __builtin_amdgcn_sched_barrier(0);
    }
    rb = rb == 2 ? 0 : rb + 1;
    sb = sb == 2 ? 0 : sb + 1;
  }

  // ---- fused epilogue: RoPE(Q,K) + K/V f32 outputs + V transpose ----
#pragma unroll
  for (int i = 0; i < AF; i++) {
    int rbase = row0 + wm * 64 + i * 16 + g * 4;
    int bb = rbase >> 11;
    int sr0 = rbase & 2047;
#pragma unroll
    for (int j = 0; j < BF; j++) {
      int cb = col0 + wn * 96 + j * 16 + fr;     // 16-col group, wave-uniform segment
      int d = cb & 127;
      if (cb < 2048) {                           // Q + RoPE (pre-scaled)
        int hq = cb >> 7;
        unsigned short* qp = qro + ((size_t)(bb * 16 + hq) * 2048 + sr0) * 128 + d;
#pragma unroll
        for (int r = 0; r < 4; r++) {
          float own = acc[i][j][r];
          float par = __shfl_xor(own, 1);
          float2 cs = cs_tab[(sr0 + r) * 64 + (d >> 1)];
          float o = (fr & 1) ? (par * cs.y + own * cs.x) : (own * cs.x - par * cs.y);
          qp[(size_t)r * 128] = f2b(o * QSCALE);
        }
      } else if (cb < 2560) {                    // K + RoPE + newk f32
        int kvh = (cb >> 7) & 3;
        unsigned short* kp = kro + ((size_t)(bb * 4 + kvh) * 2048 + sr0) * 128 + d;
        float* nk = newk + ((size_t)bb * 2048 + sr0) * 512 + kvh * 128 + d;
#pragma unroll
        for (int r = 0; r < 4; r++) {
          float own = acc[i][j][r];
          float par = __shfl_xor(own, 1);
          float2 cs = cs_tab[(sr0 + r) * 64 + (d >> 1)];
          float o = (fr & 1) ? (par * cs.y + own * cs.x) : (own * cs.x - par * cs.y);
          kp[(size_t)r * 128] = f2b(o);
          nk[(size_t)r * 512] = o;
        }
      } else {                                   // V: newv f32 + vt slot-permuted
        int kvh = (cb >> 7) & 3;
        float* nv = newv + ((size_t)bb * 2048 + sr0) * 512 + kvh * 128 + d;
        u16x4 pack;
#pragma unroll
        for (int r = 0; r < 4; r++) {
          float v = acc[i][j][r];
          nv[(size_t)r * 512] = v;
          pack[r] = f2b(v);
        }
        int kl = sr0 & 31;                       // multiple of 4
        int slotb = ((kl >> 2) & 3) * 8 + (kl >> 4) * 4;
        *reinterpret_cast<u16x4*>(vt + ((size_t)(bb * 4 + kvh) * 128 + d) * 2048
                                  + (sr0 & ~31) + slotb) = pack;
      }
    }
  }
}

// ---------------- O-projection GEMM (R11 gemm_full, BN=256) ----------------
template<int CF32, int BN>
__global__ __launch_bounds__(512, 1) void gemm_full(const unsigned short* __restrict__ A,
                                                    const unsigned short* __restrict__ B,
                                                    void* __restrict__ C,
                                                    int N, int K, int nbx) {
  constexpr int BM = 128;
  constexpr int AF = 4;
  constexpr int BF = BN / 64;
  constexpr int BH = BF / 2;
  constexpr int AL = 1;
  constexpr int BL = BN / 128;
  __shared__ unsigned short As[3][BM * 32];
  __shared__ unsigned short Bs[3][BN * 32];
  const int tid = threadIdx.x, lane = tid & 63;
  const int wid = tid >> 6, wm = wid >> 2, wn = wid & 3;
  const int cpx = gridDim.x >> 3;
  const int wgid = (blockIdx.x & 7) * cpx + (blockIdx.x >> 3);
  const int bx = wgid % nbx, by = wgid / nbx;
  const int row0 = by * BM, col0 = bx * BN;
  const int fr = lane & 15, g = lane >> 4;
  const int NT = K >> 5;

  size_t offA;
  {
    int cid = tid, R = cid >> 3, phys = cid & 7, cl = phys ^ (R & 7);
    offA = (size_t)(row0 + 2 * R + (cl >> 2)) * K + (cl & 3) * 8;
  }
  size_t offB[BL];
#pragma unroll
  for (int l = 0; l < BL; l++) {
    int cid = tid + l * 512, R = cid >> 3, phys = cid & 7, cl = phys ^ (R & 7);
    offB[l] = (size_t)(col0 + 2 * R + (cl >> 2)) * K + (cl & 3) * 8;
  }

  auto stage_p0 = [&](int t, int sb) {
    int k0 = t * 32;
    glds16(A + offA + k0, &As[sb][tid * 8]);
    glds16(B + offB[0] + k0, &Bs[sb][tid * 8]);
  };
  auto stage_p1 = [&](int t, int sb) {
    int k0 = t * 32;
#pragma unroll
    for (int l = 1; l < BL; l++)
      glds16(B + offB[l] + k0, &Bs[sb][(tid + l * 512) * 8]);
  };

  auto ldfrag = [&](const unsigned short* buf, int row) {
    int R = row >> 1;
    int phys = ((((row & 1) << 2) | g) ^ (R & 7));
    return *reinterpret_cast<const bf16x8*>(&buf[R * 64 + phys * 8]);
  };

  f32x4 acc[AF][BF];
#pragma unroll
  for (int i = 0; i < AF; i++)
#pragma unroll
    for (int j = 0; j < BF; j++) acc[i][j] = f32x4{0.f, 0.f, 0.f, 0.f};

  stage_p0(0, 0); stage_p1(0, 0);
  stage_p0(1, 1); stage_p1(1, 1);
  if constexpr (AL + BL == 4) asm volatile("s_waitcnt vmcnt(4)" ::: "memory");
  else                        asm volatile("s_waitcnt vmcnt(3)" ::: "memory");
  __builtin_amdgcn_s_barrier();
  __builtin_amdgcn_sched_barrier(0);

  int rb = 0, sb = 2;
#pragma unroll 1
  for (int t = 0; t < NT; ++t) {
    const unsigned short* Ar = &As[rb][0];
    const unsigned short* Br = &Bs[rb][0];

    bf16x8 af[AF], bfr[BF];
#pragma unroll
    for (int mf = 0; mf < AF; mf++) af[mf] = ldfrag(Ar, wm * 64 + mf * 16 + fr);
#pragma unroll
    for (int nf = 0; nf < BH; nf++) bfr[nf] = ldfrag(Br, wn * (BN / 4) + nf * 16 + fr);
    if (t + 2 < NT) stage_p0(t + 2, sb);
    __builtin_amdgcn_s_barrier();
    asm volatile("s_waitcnt lgkmcnt(0)" ::: "memory");
    __builtin_amdgcn_sched_barrier(0);
    __builtin_amdgcn_s_setprio(1);
#pragma unroll
    for (int mf = 0; mf < AF; mf++)
#pragma unroll
      for (int nf = 0; nf < BH; nf++)
        acc[mf][nf] = __builtin_amdgcn_mfma_f32_16x16x32_bf16(af[mf], bfr[nf], acc[mf][nf], 0, 0, 0);
    __builtin_amdgcn_s_setprio(0);
    __builtin_amdgcn_sched_barrier(0);
    __builtin_amdgcn_s_barrier();

#pragma unroll
    for (int nf = BH; nf < BF; nf++) bfr[nf] = ldfrag(Br, wn * (BN / 4) + nf * 16 + fr);
    if (t + 2 < NT) stage_p1(t + 2, sb);
    __builtin_amdgcn_s_barrier();
    asm volatile("s_waitcnt lgkmcnt(0)" ::: "memory");
    __builtin_amdgcn_sched_barrier(0);
    __builtin_amdgcn_s_setprio(1);
#pragma unroll
    for (int mf = 0; mf < AF; mf++)
#pragma unroll
      for (int nf = BH; nf < BF; nf++)
        acc[mf][nf] = __builtin_amdgcn_mfma_f32_16x16x32_bf16(af[mf], bfr[nf], acc[mf][nf], 0, 0, 0);
    __builtin_amdgcn_s_setprio(0);
    __builtin_amdgcn_sched_barrier(0);

    if (t + 1 < NT) {
      if (t + 2 < NT) {
        if constexpr (AL + BL == 4) asm volatile("s_waitcnt vmcnt(4)" ::: "memory");
        else                        asm volatile("s_waitcnt vmcnt(3)" ::: "memory");
      } else {
        asm volatile("s_waitcnt vmcnt(0)" ::: "memory");
      }
      __builtin_amdgcn_s_barrier();
      __builtin_amdgcn_sched_barrier(0);
    }
    rb = rb == 2 ? 0 : rb + 1;
    sb = sb == 2 ? 0 : sb + 1;
  }

#pragma unroll
  for (int i = 0; i < AF; i++) {
#pragma unroll
    for (int j = 0; j < BF; j++) {
      int rbase = row0 + wm * 64 + i * 16 + g * 4;
      int cb = col0 + wn * (BN / 4) + j * 16 + fr;
#pragma unroll
      for (int r = 0; r < 4; r++) {
        if (CF32)
          reinterpret_cast<float*>(C)[(size_t)(rbase + r) * N + cb] = acc[i][j][r];
        else
          reinterpret_cast<unsigned short*>(C)[(size_t)(rbase + r) * N + cb] = f2b(acc[i][j][r]);
      }
    }
  }
}

// ---------------- flash attention: block = (q-tile16, kvh, b), 4 waves = 4 heads
__global__ __launch_bounds__(256, 4) void attn_kernel(const unsigned short* __restrict__ qro,
                                                      const unsigned short* __restrict__ kro,
                                                      const unsigned short* __restrict__ vt,
                                                      unsigned short* __restrict__ out) {
  __shared__ unsigned short Ks[2][32 * 128];   // [kv][d], rows 256B, swizzled
  __shared__ unsigned short Vs[2][64 * 64];    // paired-d rows 128B, swizzled
  const int tid = threadIdx.x, lane = tid & 63, w = tid >> 6;
  const int kvhb = blockIdx.x & 7;             // XCD pin: same (kvh,b) -> same XCD
  const int kvh = kvhb & 3, b = kvhb >> 2;
  const int t = 127 - (blockIdx.x >> 3);       // heavy-first
  const int h = kvh * 4 + w;                   // wave = one q-head
  const int qbase = t * 16;
  const int fr = lane & 15, g = lane >> 4, fk = g * 8;
  const unsigned short* Kp = kro + (size_t)(b * 4 + kvh) * 2048 * 128;
  const unsigned short* Vtp = vt + (size_t)(b * 4 + kvh) * 128 * 2048;
  const unsigned short* Qp = qro + ((size_t)(b * 16 + h) * 2048 + qbase) * 128;

  bf16x8 qf[4];
#pragma unroll
  for (int kk = 0; kk < 4; kk++)
    qf[kk] = *reinterpret_cast<const bf16x8*>(Qp + fr * 128 + kk * 32 + fk);

  u16x8 onesu;
#pragma unroll
  for (int j = 0; j < 8; j++) onesu[j] = 0x3F80;  // bf16 1.0
  bf16x8 ones = __builtin_bit_cast(bf16x8, onesu);

  f32x4 o[8];
#pragma unroll
  for (int dt = 0; dt < 8; dt++) o[dt] = f32x4{0.f, 0.f, 0.f, 0.f};
  f32x4 dacc = f32x4{0.f, 0.f, 0.f, 0.f};
  const int qrow_s = qbase + fr;
  const int nfull = (qbase >= 31) ? ((qbase - 31) >> 5) + 1 : 0;
  const int niter = nfull + 1;

  const int krow = w * 8 + (lane >> 4);        // K stage rows (+j*4)
  const int kcol = lane & 15;
  const int vrow = w * 16 + (lane >> 3);       // V stage rows, paired-d (+j*8)
  const int vcol = lane & 7;

  auto stage = [&](int kv0, int buf) {
    unsigned short* Kb = &Ks[buf][0];
    unsigned short* Vb = &Vs[buf][0];
#pragma unroll
    for (int j = 0; j < 2; j++) {
      int r = krow + j * 4;
      glds16(Kp + (size_t)(kv0 + r) * 128 + ((kcol ^ (r & 7)) * 8),
             Kb + (w * 8 + j * 4) * 128);
    }
#pragma unroll
    for (int j = 0; j < 2; j++) {
      int r = vrow + j * 8;
      int u = vcol ^ (r & 7);
      int d = 2 * r + (u >> 2);
      glds16(Vtp + (size_t)d * 2048 + kv0 + (u & 3) * 8,
             Vb + (w * 16 + j * 8) * 64);
    }
  };

  auto step = [&](int kv0, bool mask, int buf) {
    const unsigned short* Kb = &Ks[buf][0];
    const unsigned short* Vb = &Vs[buf][0];
    f32x4 sc[2];
    sc[0] = sc[1] = f32x4{0.f, 0.f, 0.f, 0.f};
    __builtin_amdgcn_s_setprio(1);
#pragma unroll
    for (int kk = 0; kk < 4; kk++) {
      int blk = ((kk * 4 + g) ^ (fr & 7)) * 8;
      bf16x8 ka0 = *reinterpret_cast<const bf16x8*>(Kb + (fr +  0) * 128 + blk);
      bf16x8 ka1 = *reinterpret_cast<const bf16x8*>(Kb + (fr + 16) * 128 + blk);
      sc[0] = __builtin_amdgcn_mfma_f32_16x16x32_bf16(ka0, qf[kk], sc[0], 0, 0, 0);
      sc[1] = __builtin_amdgcn_mfma_f32_16x16x32_bf16(ka1, qf[kk], sc[1], 0, 0, 0);
    }
    __builtin_amdgcn_s_setprio(0);
#pragma unroll
    for (int s = 0; s < 2; s++)
#pragma unroll
      for (int r = 0; r < 4; r++) {
        float v = sc[s][r];
        if (mask && (kv0 + 16 * s + 4 * g + r > qrow_s)) v = -1e30f;
        sc[s][r] = __builtin_amdgcn_exp2f(v);
      }
    u16x8 pau;
#pragma unroll
    for (int j = 0; j < 4; j++) {
      pau[j]     = f2b(sc[0][j]);
      pau[4 + j] = f2b(sc[1][j]);
    }
    bf16x8 pa = __builtin_bit_cast(bf16x8, pau);
    dacc = __builtin_amdgcn_mfma_f32_16x16x32_bf16(pa, ones, dacc, 0, 0, 0);
    __builtin_amdgcn_s_setprio(1);
#pragma unroll
    for (int dt = 0; dt < 8; dt++) {
      int jr = dt * 8 + (fr >> 1);
      int c = ((fr & 1) * 4 + g) ^ (fr >> 1);
      bf16x8 vf = *reinterpret_cast<const bf16x8*>(Vb + jr * 64 + c * 8);
      o[dt] = __builtin_amdgcn_mfma_f32_16x16x32_bf16(pa, vf, o[dt], 0, 0, 0);
    }
    __builtin_amdgcn_s_setprio(0);
  };

  stage(0, 0);
  int buf = 0;
  for (int i = 0; i < niter; i++) {
    __syncthreads();                 // tile i staged; prior reads of buf^1 done
    if (i + 1 < niter) stage((i + 1) * 32, buf ^ 1);
    step(i * 32, i == nfull, buf);
    buf ^= 1;
  }

#pragma unroll
  for (int r = 0; r < 4; r++) {
    float inv = 1.0f / dacc[r];
    int qrow = qbase + g * 4 + r;
    size_t rowoff = ((size_t)b * 2048 + qrow) * 2048 + (size_t)h * 128;
#pragma unroll
    for (int dt = 0; dt < 8; dt++)
      out[rowoff + dt * 16 + fr] = f2b(o[dt][r] * inv);
  }
}

// ---------------- launch ---------------------------------------------------
extern "C" void kernel_launch(void* const* d_in, const int* in_sizes, int n_in,
                              void* d_out, int out_size, void* d_ws, size_t ws_size,
                              hipStream_t stream) {
  const float* x  = (const float*)d_in[0];
  const float* wq = (const float*)d_in[1];
  const float* wk = (const float*)d_in[2];
  const float* wv = (const float*)d_in[3];
  const float* wo = (const float*)d_in[4];
  const float* freqs = (const float*)d_in[5];

  char* ws = (char*)d_ws;
  unsigned short* xb    = (unsigned short*)(ws);             // 16 MB, reused as attn out
  unsigned short* attn  = xb;
  unsigned short* wqkvb = (unsigned short*)(ws + 16777216);  // [3072][2048] bf16
  unsigned short* wob   = (unsigned short*)(ws + 29360128);
  float2*         cstab = (float2*)(ws + 37748736);          // [2048][64] cos/sin, 1 MB
  unsigned short* qro   = (unsigned short*)(ws + 62914560);
  unsigned short* kro   = (unsigned short*)(ws + 79691776);
  unsigned short* vt    = (unsigned short*)(ws + 83886080);

  float* out_o = (float*)d_out;
  float* out_k = (float*)d_out + 8388608;
  float* out_v = (float*)d_out + 10485760;

  cvt_fused<<<9728, 256, 0, stream>>>(x, wq, wk, wv, wo, freqs, xb, wqkvb, wob, cstab);

  // QKV GEMM + fused RoPE/V-transpose: grid 32x8 = 256 blocks = full chip
  gemm_qkv<<<256, 512, 0, stream>>>(xb, wqkvb, cstab, qro, kro, vt, out_k, out_v, 2048);

  attn_kernel<<<1024, 256, 0, stream>>>(qro, kro, vt, attn);

  // O: BM=128 x BN=256 -> grid 32x8 = 256 blocks = full chip, 1 round
  gemm_full<1, 256><<<256, 512, 0, stream>>>(attn, wob, out_o, 2048, 2048, 8);
}